// Round 8
// baseline (48.601 us; speedup 1.0000x reference)
//
#include <hip/hip_runtime.h>
#include <math.h>
#include <stdint.h>

#define NTOK 8192
#define HID  4096
#define NEXP 64
#define TOPK 8

typedef float    f32x4 __attribute__((ext_vector_type(4)));
typedef _Float16 f16x8 __attribute__((ext_vector_type(8)));

// ws layout:
//   [0, 1MB)   : wsW — 64 ktiles x 16KB. Tile kt: [hi: 512 x f16x8][lo: 512 x f16x8],
//                entry index r*8 + (c ^ (r&7)), r=expert 0..63, c=k-chunk 0..7 (8 f16 each).
//   [1MB, 9MB) : logits partials [4][NTOK][64] f32  (x2048 scale)

__device__ __forceinline__ void cvt_hilo(f32x4 a, f32x4 b, f16x8& hi, f16x8& lo)
{
    float x[8] = {a.x, a.y, a.z, a.w, b.x, b.y, b.z, b.w};
#pragma unroll
    for (int j = 0; j < 8; ++j) {
        const _Float16 h = (_Float16)x[j];
        hi[j] = h;
        lo[j] = (_Float16)(x[j] - (float)h);
    }
}

__device__ __forceinline__ void gll16(const void* g, void* l) {
    __builtin_amdgcn_global_load_lds(
        (const __attribute__((address_space(1))) uint32_t*)g,
        (__attribute__((address_space(3))) uint32_t*)l, 16, 0, 0);
}

// ---------------------------------------------------------------------
// k0: W fp32 -> pre-swizzled f16 hi/lo tiles (x2048). 128 blocks x 256.
// thread -> (kt, r, c): reads W[r][kt*64 + c*8 .. +7].
// ---------------------------------------------------------------------
__global__ __launch_bounds__(256)
void k0_wsplit(const float* __restrict__ W, char* __restrict__ wsW)
{
    const int gidx = blockIdx.x * 256 + threadIdx.x;   // 0..32767
    const int kt = gidx >> 9;
    const int r  = (gidx >> 3) & 63;
    const int c  = gidx & 7;

    const float* src = W + (size_t)r * HID + kt * 64 + c * 8;
    const f32x4 w0 = *(const f32x4*)src;
    const f32x4 w1 = *(const f32x4*)(src + 4);
    f16x8 hi, lo;
    cvt_hilo(w0 * 2048.0f, w1 * 2048.0f, hi, lo);

    f16x8* tile = (f16x8*)(wsW + (size_t)kt * 16384);
    const int cp = c ^ (r & 7);
    tile[r * 8 + cp]       = hi;
    tile[512 + r * 8 + cp] = lo;
}

// ---------------------------------------------------------------------
// k1: partial logits (x2048). 512 blocks x 256 thr (4 waves token-split,
// block k-quarter m). Per ktile (64k): stage next tile via global_load_lds
// (dbuf, 1 barrier), 2 MFMA steps of 32k reading B from swizzled LDS.
// A: f32 from HBM, depth-2 named ring, in-reg hi/lo split.
// ---------------------------------------------------------------------
#define AL(SET, S) do { const float* _p = ha + (S) * 32;                      \
    SET##0 = *(const f32x4*)_p; SET##1 = *(const f32x4*)(_p + 4); } while (0)

#define STEPU(SET, KS) do {                                                   \
    f16x8 _ah, _al; cvt_hilo(SET##0, SET##1, _ah, _al);                       \
    const int _ci = ((KS) * 4 + kg) ^ (lr & 7);                               \
    _Pragma("unroll")                                                         \
    for (int _e4 = 0; _e4 < 4; ++_e4) {                                       \
        const int _ix = _e4 * 128 + lr * 8 + _ci;                             \
        const f16x8 _bh = *(const f16x8*)&bt[_ix * 8];                        \
        const f16x8 _bl = *(const f16x8*)&bt[4096 + _ix * 8];                 \
        accH[_e4] = __builtin_amdgcn_mfma_f32_16x16x32_f16(_ah, _bh, accH[_e4], 0, 0, 0); \
        accM[_e4] = __builtin_amdgcn_mfma_f32_16x16x32_f16(_ah, _bl, accM[_e4], 0, 0, 0); \
        accL[_e4] = __builtin_amdgcn_mfma_f32_16x16x32_f16(_al, _bh, accL[_e4], 0, 0, 0); \
    } } while (0)

__global__ __launch_bounds__(256, 3)
void k1_partial(const float* __restrict__ Hm, const char* __restrict__ wsW,
                float* __restrict__ lgp)
{
    __shared__ _Float16 B[2][8192];     // 2 x 16KB (hi 8KB + lo 8KB per tile)

    const int tid  = threadIdx.x;
    const int wave = tid >> 6;
    const int l    = tid & 63;
    const int lr   = l & 15;            // A row (token) / B col (expert) in tile
    const int kg   = l >> 4;            // k-subgroup (8 consecutive k)
    const int tg   = blockIdx.x >> 2;
    const int m    = blockIdx.x & 3;
    const int tok0 = tg * 64 + wave * 16;

    const float* ha = Hm + (size_t)(tok0 + lr) * HID + m * 1024 + kg * 8;
    const char*  wsrc = wsW + (size_t)m * 16 * 16384 + tid * 16;  // +i*4096 per round
    const int    ldsoff = wave * 512;   // f16 units; uniform per wave (+lane*16B implicit)

    f32x4 accH[4], accM[4], accL[4];
#pragma unroll
    for (int e = 0; e < 4; ++e) {
        accH[e] = (f32x4)(0.0f); accM[e] = (f32x4)(0.0f); accL[e] = (f32x4)(0.0f);
    }

    // A ring prologue (steps 0,1); stage ktile 0 -> buf 0
    f32x4 Aa0, Aa1, Ab0, Ab1;
    AL(Aa, 0); AL(Ab, 1);
#pragma unroll
    for (int i = 0; i < 4; ++i)
        gll16(wsrc + i * 4096, &B[0][i * 2048 + ldsoff]);
    __syncthreads();

#pragma unroll 1
    for (int kt = 0; kt < 16; ++kt) {
        const int p = kt & 1;
        if (kt < 15) {                  // stage ktile kt+1 into other buffer
            const char* s = wsrc + (size_t)(kt + 1) * 16384;
#pragma unroll
            for (int i = 0; i < 4; ++i)
                gll16(s + i * 4096, &B[p ^ 1][i * 2048 + ldsoff]);
        }
        const _Float16* bt = &B[p][0];
        const int S0 = 2 * kt;
        STEPU(Aa, 0); { const int Sn = (S0 + 2 < 32) ? S0 + 2 : 31; AL(Aa, Sn); }
        STEPU(Ab, 1); { const int Sn = (S0 + 3 < 32) ? S0 + 3 : 31; AL(Ab, Sn); }
        __syncthreads();                // drains gll; next tile ready
    }

    // merge banks, write partial slice. C/D: col=lane&15, row=(lane>>4)*4+r.
    float* wsw = lgp + ((size_t)m * NTOK + tok0) * 64;
#pragma unroll
    for (int e4 = 0; e4 < 4; ++e4) {
        const f32x4 a = accH[e4] + accM[e4] + accL[e4];
#pragma unroll
        for (int r = 0; r < 4; ++r)
            wsw[(kg * 4 + r) * 64 + e4 * 16 + lr] = a[r];
    }
}

// ---------------------------------------------------------------------
// k2: fixed-order 4-slice reduce + softmax + top-8 rank-count.
// 512 blocks x 256 thr; each wave: 4 tokens sequentially, lane = expert.
// Sum and rank via identical-order LDS reads (deterministic, lane-uniform).
// ---------------------------------------------------------------------
__global__ __launch_bounds__(256)
void k2_finish(const float* __restrict__ lgp, float* __restrict__ out)
{
    __shared__ __align__(16) float sc[4][64];
    const int tid  = threadIdx.x;
    const int wave = tid >> 6;
    const int lane = tid & 63;
    float* outw = out;
    float* outi = out + (size_t)NTOK * TOPK;

#pragma unroll 1
    for (int t = 0; t < 4; ++t) {
        const int tok = blockIdx.x * 16 + wave * 4 + t;
        const float* p = lgp + (size_t)tok * 64 + lane;
        const float lgv = ((p[0] + p[(size_t)NTOK * 64])
                         + (p[(size_t)2 * NTOK * 64] + p[(size_t)3 * NTOK * 64]))
                         * (1.0f / 2048.0f);

        float mx = lgv;
#pragma unroll
        for (int off = 32; off; off >>= 1) mx = fmaxf(mx, __shfl_xor(mx, off));
        const float pv = expf(lgv - mx);

        sc[wave][lane] = pv;
        __syncthreads();

        float ss = 0.f;
        int rank = 0;
#pragma unroll
        for (int j4 = 0; j4 < 16; ++j4) {
            const f32x4 v = *(const f32x4*)&sc[wave][j4 * 4];
#pragma unroll
            for (int u = 0; u < 4; ++u) {
                const int j = j4 * 4 + u;
                ss += v[u];
                rank += (v[u] > pv || (v[u] == pv && j < lane)) ? 1 : 0;
            }
        }
        if (rank < TOPK) {
            outw[(size_t)tok * TOPK + rank] = pv / ss;
            outi[(size_t)tok * TOPK + rank] = (float)lane;
        }
        __syncthreads();
    }
}

extern "C" void kernel_launch(void* const* d_in, const int* in_sizes, int n_in,
                              void* d_out, int out_size, void* d_ws, size_t ws_size,
                              hipStream_t stream) {
    (void)in_sizes; (void)n_in; (void)out_size; (void)ws_size;
    const float* h = (const float*)d_in[0];   // [8192, 4096] fp32
    const float* w = (const float*)d_in[1];   // [64, 4096]  fp32
    float* out = (float*)d_out;

    char*  wsW = (char*)d_ws;                         // 1 MB swizzled f16 W
    float* lgp = (float*)((char*)d_ws + (1 << 20));   // 8 MB logits partials

    k0_wsplit<<<128, 256, 0, stream>>>(w, wsW);
    k1_partial<<<512, 256, 0, stream>>>(h, wsW, lgp);
    k2_finish<<<512, 256, 0, stream>>>(lgp, out);
}

// Round 9
// 44.767 us; speedup vs baseline: 1.0856x; 1.0856x over previous
//
#include <hip/hip_runtime.h>
#include <math.h>
#include <stdint.h>

#define NTOK 8192
#define HID  4096
#define NEXP 64
#define TOPK 8

typedef float    f32x4 __attribute__((ext_vector_type(4)));
typedef _Float16 f16x8 __attribute__((ext_vector_type(8)));

// ws layout:
//   [0, 1MB)   : wsW — 32 ktiles (128 k each) x 32KB. Tile kt stores, at linear
//                16B-entry e (0..2047):  region hi (e<1024) / lo (e>=1024);
//                within region: r = e>>4, sl = e&15, holding W chunk c = sl ^ (r&7)
//                (8 f16 = k [kt*128 + c*8, +8) of expert r, x2048 scale).
//                This is exactly the LDS image k1 wants -> gll sources are LINEAR.
//   [1MB, 9MB) : logits partials [4][NTOK][64] f32 (x2048 scale)

__device__ __forceinline__ void cvt_hilo(f32x4 a, f32x4 b, f16x8& hi, f16x8& lo)
{
    float x[8] = {a.x, a.y, a.z, a.w, b.x, b.y, b.z, b.w};
#pragma unroll
    for (int j = 0; j < 8; ++j) {
        const _Float16 h = (_Float16)x[j];
        hi[j] = h;
        lo[j] = (_Float16)(x[j] - (float)h);
    }
}

__device__ __forceinline__ void gll16(const void* g, void* l) {
    __builtin_amdgcn_global_load_lds(
        (const __attribute__((address_space(1))) uint32_t*)g,
        (__attribute__((address_space(3))) uint32_t*)l, 16, 0, 0);
}

// ---------------------------------------------------------------------
// k0: W fp32 -> pre-swizzled f16 hi/lo ktiles (x2048). 128 blocks x 256.
// thread -> (kt, r, sl); data chunk c = sl ^ (r&7).
// ---------------------------------------------------------------------
__global__ __launch_bounds__(256)
void k0_wsplit(const float* __restrict__ W, char* __restrict__ wsW)
{
    const int gidx = blockIdx.x * 256 + threadIdx.x;   // 0..32767
    const int kt = gidx >> 10;          // 32 tiles of 128 k
    const int r  = (gidx >> 4) & 63;
    const int sl = gidx & 15;
    const int c  = sl ^ (r & 7);

    const float* src = W + (size_t)r * HID + kt * 128 + c * 8;
    const f32x4 w0 = *(const f32x4*)src;
    const f32x4 w1 = *(const f32x4*)(src + 4);
    f16x8 hi, lo;
    cvt_hilo(w0 * 2048.0f, w1 * 2048.0f, hi, lo);

    f16x8* tile = (f16x8*)(wsW + (size_t)kt * 32768);
    tile[r * 16 + sl]        = hi;      // entries 0..1023
    tile[1024 + r * 16 + sl] = lo;      // entries 1024..2047
}

// ---------------------------------------------------------------------
// k1: partial logits (x2048). 512 blocks x 256 thr (4 waves token-split,
// block k-quarter m). 8 ktiles of 128k, double-buffered 32KB LDS tiles:
// per ktile: issue 8 gll for next tile, 4 MFMA steps (A-ring depth 8),
// one barrier.  A: f32 HBM/L3, in-reg hi/lo split.  B: swizzled LDS.
// ---------------------------------------------------------------------
#define AL(SET, S) do { const float* _p = ha + (S) * 32;                      \
    SET##0 = *(const f32x4*)_p; SET##1 = *(const f32x4*)(_p + 4); } while (0)
#define ALG(SET, S) do { if ((S) < 32) AL(SET, S); } while (0)

#define STEPU(SET, KS) do {                                                   \
    f16x8 _ah, _al; cvt_hilo(SET##0, SET##1, _ah, _al);                       \
    _Pragma("unroll")                                                         \
    for (int _e4 = 0; _e4 < 4; ++_e4) {                                       \
        const int _r  = _e4 * 16 + lr;                                        \
        const int _sl = ((KS) * 4 + kg) ^ (lr & 7);                           \
        const f16x8 _bh = *(const f16x8*)&bt[(_r * 16 + _sl) * 8];            \
        const f16x8 _bl = *(const f16x8*)&bt[8192 + (_r * 16 + _sl) * 8];     \
        accH[_e4] = __builtin_amdgcn_mfma_f32_16x16x32_f16(_ah, _bh, accH[_e4], 0, 0, 0); \
        accM[_e4] = __builtin_amdgcn_mfma_f32_16x16x32_f16(_ah, _bl, accM[_e4], 0, 0, 0); \
        accL[_e4] = __builtin_amdgcn_mfma_f32_16x16x32_f16(_al, _bh, accL[_e4], 0, 0, 0); \
    } } while (0)

#define STAGE(KT, BUF) do {                                                   \
    const char* _s = wsrc + (KT) * 32768;                                     \
    _Pragma("unroll")                                                         \
    for (int _t = 0; _t < 8; ++_t)                                            \
        gll16(_s + _t * 4096, (void*)&BT[BUF][_t * 2048 + tid * 8]);          \
} while (0)

#define KTILE(KT, SA, SB, SC, SD) do {                                        \
    if ((KT) < 7) STAGE((KT) + 1, ((KT) & 1) ^ 1);                            \
    const _Float16* bt = &BT[(KT) & 1][0];                                    \
    STEPU(SA, 0); ALG(SA, (KT) * 4 + 8);                                      \
    STEPU(SB, 1); ALG(SB, (KT) * 4 + 9);                                      \
    STEPU(SC, 2); ALG(SC, (KT) * 4 + 10);                                     \
    STEPU(SD, 3); ALG(SD, (KT) * 4 + 11);                                     \
    __syncthreads();                                                          \
} while (0)

__global__ __launch_bounds__(256, 2)
void k1_partial(const float* __restrict__ Hm, const char* __restrict__ wsW,
                float* __restrict__ lgp)
{
    __shared__ _Float16 BT[2][16384];   // 2 x 32KB ktile images

    const int tid  = threadIdx.x;
    const int wave = tid >> 6;
    const int l    = tid & 63;
    const int lr   = l & 15;            // A row (token) / B col (expert) in tile
    const int kg   = l >> 4;            // k-subgroup (8 consecutive k)
    const int tg   = blockIdx.x >> 2;
    const int m    = blockIdx.x & 3;
    const int tok0 = tg * 64 + wave * 16;

    const float* ha   = Hm + (size_t)(tok0 + lr) * HID + m * 1024 + kg * 8;
    const char*  wsrc = wsW + (size_t)m * 8 * 32768 + tid * 16;

    f32x4 accH[4], accM[4], accL[4];
#pragma unroll
    for (int e = 0; e < 4; ++e) {
        accH[e] = (f32x4)(0.0f); accM[e] = (f32x4)(0.0f); accL[e] = (f32x4)(0.0f);
    }

    // prologue: stage ktile 0, fill depth-8 A ring (steps 0..7)
    STAGE(0, 0);
    f32x4 Aa0, Aa1, Ab0, Ab1, Ac0, Ac1, Ad0, Ad1;
    f32x4 Ae0, Ae1, Af0, Af1, Ag0, Ag1, Ah0, Ah1;
    AL(Aa, 0); AL(Ab, 1); AL(Ac, 2); AL(Ad, 3);
    AL(Ae, 4); AL(Af, 5); AL(Ag, 6); AL(Ah, 7);
    __syncthreads();

    KTILE(0, Aa, Ab, Ac, Ad);
    KTILE(1, Ae, Af, Ag, Ah);
    KTILE(2, Aa, Ab, Ac, Ad);
    KTILE(3, Ae, Af, Ag, Ah);
    KTILE(4, Aa, Ab, Ac, Ad);
    KTILE(5, Ae, Af, Ag, Ah);
    KTILE(6, Aa, Ab, Ac, Ad);
    KTILE(7, Ae, Af, Ag, Ah);

    // merge banks, write partial slice. C/D: col=lane&15, row=(lane>>4)*4+r.
    float* wsw = lgp + ((size_t)m * NTOK + tok0) * 64;
#pragma unroll
    for (int e4 = 0; e4 < 4; ++e4) {
        const f32x4 a = accH[e4] + accM[e4] + accL[e4];
#pragma unroll
        for (int r = 0; r < 4; ++r)
            wsw[(kg * 4 + r) * 64 + e4 * 16 + lr] = a[r];
    }
}

// ---------------------------------------------------------------------
// k2: fixed-order 4-slice reduce + softmax + top-8 rank-count.
// 2048 blocks x 256 thr; 1 token per wave (proven R7 form).
// ---------------------------------------------------------------------
__global__ __launch_bounds__(256)
void k2_finish(const float* __restrict__ lgp, float* __restrict__ out)
{
    __shared__ __align__(16) float sc[4][64];
    const int tid  = threadIdx.x;
    const int wave = tid >> 6;
    const int lane = tid & 63;
    float* outw = out;
    float* outi = out + (size_t)NTOK * TOPK;

    const int tok = blockIdx.x * 4 + wave;
    const float* p = lgp + (size_t)tok * 64 + lane;
    const float lgv = ((p[0] + p[(size_t)NTOK * 64])
                     + (p[(size_t)2 * NTOK * 64] + p[(size_t)3 * NTOK * 64]))
                     * (1.0f / 2048.0f);

    float mx = lgv;
#pragma unroll
    for (int off = 32; off; off >>= 1) mx = fmaxf(mx, __shfl_xor(mx, off));
    const float pv = expf(lgv - mx);
    float ss = pv;
#pragma unroll
    for (int off = 32; off; off >>= 1) ss += __shfl_xor(ss, off);
    ss = __shfl(ss, 0);                 // identical denominator on all lanes
    const float sval = pv / ss;

    sc[wave][lane] = sval;
    __syncthreads();

    int rank = 0;
#pragma unroll
    for (int j4 = 0; j4 < 16; ++j4) {
        const f32x4 v = *(const f32x4*)&sc[wave][j4 * 4];
#pragma unroll
        for (int u = 0; u < 4; ++u) {
            const int j = j4 * 4 + u;
            rank += (v[u] > sval || (v[u] == sval && j < lane)) ? 1 : 0;
        }
    }
    if (rank < TOPK) {
        outw[(size_t)tok * TOPK + rank] = sval;
        outi[(size_t)tok * TOPK + rank] = (float)lane;
    }
}

extern "C" void kernel_launch(void* const* d_in, const int* in_sizes, int n_in,
                              void* d_out, int out_size, void* d_ws, size_t ws_size,
                              hipStream_t stream) {
    (void)in_sizes; (void)n_in; (void)out_size; (void)ws_size;
    const float* h = (const float*)d_in[0];   // [8192, 4096] fp32
    const float* w = (const float*)d_in[1];   // [64, 4096]  fp32
    float* out = (float*)d_out;

    char*  wsW = (char*)d_ws;                         // 1 MB swizzled f16 W tiles
    float* lgp = (float*)((char*)d_ws + (1 << 20));   // 8 MB logits partials

    k0_wsplit<<<128, 256, 0, stream>>>(w, wsW);
    k1_partial<<<512, 256, 0, stream>>>(h, wsW, lgp);
    k2_finish<<<NTOK / 4, 256, 0, stream>>>(lgp, out);
}